// Round 1
// baseline (170.340 us; speedup 1.0000x reference)
//
#include <hip/hip_runtime.h>
#include <cstddef>

#define OUT_FEATS 4096
#define IN_FEATS  16384
#define EPS 1e-8f

// ---------------------------------------------------------------------------
// Kernel 1: denom = sum(v*v) + eps   (one block, 256 threads)
// ---------------------------------------------------------------------------
__global__ void k_denom(const float* __restrict__ v, float* __restrict__ denom) {
    __shared__ float red[4];
    float s = 0.f;
    for (int i = threadIdx.x; i < OUT_FEATS; i += 256) {
        float x = v[i];
        s += x * x;
    }
    // wave64 butterfly reduce
    #pragma unroll
    for (int off = 32; off > 0; off >>= 1) s += __shfl_down(s, off, 64);
    if ((threadIdx.x & 63) == 0) red[threadIdx.x >> 6] = s;
    __syncthreads();
    if (threadIdx.x == 0) {
        float t = red[0] + red[1] + red[2] + red[3];
        *denom = t + EPS;
    }
}

// ---------------------------------------------------------------------------
// Kernel 2: split-K partial GEMV  partial[chunk][j] = sum_{r in chunk} v[r]*A[r][j]
// grid = (IN_FEATS/4/256, nchunk), block = 256. Each thread owns one float4
// of columns. Coalesced 16B/lane loads of A; v[r] is uniform -> scalar load.
// ---------------------------------------------------------------------------
__global__ void k_gemv_partial(const float* __restrict__ A,
                               const float* __restrict__ v,
                               float* __restrict__ partial,
                               int rows_per_chunk) {
    const int col4 = blockIdx.x * 256 + threadIdx.x;       // float4 column idx [0, 4096)
    const int r0 = blockIdx.y * rows_per_chunk;
    int r1 = r0 + rows_per_chunk;
    if (r1 > OUT_FEATS) r1 = OUT_FEATS;

    const float4* __restrict__ A4 = (const float4*)A;
    float4 acc = make_float4(0.f, 0.f, 0.f, 0.f);
    for (int r = r0; r < r1; ++r) {
        const float vr = v[r];
        const float4 a = A4[(size_t)r * (IN_FEATS / 4) + col4];
        acc.x += vr * a.x;
        acc.y += vr * a.y;
        acc.z += vr * a.z;
        acc.w += vr * a.w;
    }
    ((float4*)partial)[(size_t)blockIdx.y * (IN_FEATS / 4) + col4] = acc;
}

// ---------------------------------------------------------------------------
// Kernel 3: coeff[j] = (sum_c partial[c][j]) / denom
// grid = IN_FEATS/4/256 = 16 blocks of 256
// ---------------------------------------------------------------------------
__global__ void k_reduce(const float* __restrict__ partial,
                         const float* __restrict__ denom,
                         float* __restrict__ coeff,
                         int nchunk) {
    const int j4 = blockIdx.x * 256 + threadIdx.x;
    const float4* __restrict__ P4 = (const float4*)partial;
    float4 s = make_float4(0.f, 0.f, 0.f, 0.f);
    for (int c = 0; c < nchunk; ++c) {
        const float4 p = P4[(size_t)c * (IN_FEATS / 4) + j4];
        s.x += p.x; s.y += p.y; s.z += p.z; s.w += p.w;
    }
    const float d = *denom;
    s.x /= d; s.y /= d; s.z /= d; s.w /= d;
    ((float4*)coeff)[j4] = s;
}

// ---------------------------------------------------------------------------
// Kernel 4: out[i][j] = A[i][j] - v[i]*coeff[j]   (fully coalesced float4)
// row is uniform within each 256-thread block (4096 float4 per row).
// ---------------------------------------------------------------------------
__global__ void k_apply(const float* __restrict__ A,
                        const float* __restrict__ v,
                        const float* __restrict__ coeff,
                        float* __restrict__ out) {
    const size_t idx = (size_t)blockIdx.x * 256 + threadIdx.x;   // float4 index
    const int row = (int)(idx >> 12);          // / (IN_FEATS/4 = 4096)
    const int c4  = (int)(idx & 4095);
    const float4 a  = ((const float4*)A)[idx];
    const float4 cf = ((const float4*)coeff)[c4];
    const float vr  = v[row];
    float4 o;
    o.x = a.x - vr * cf.x;
    o.y = a.y - vr * cf.y;
    o.z = a.z - vr * cf.z;
    o.w = a.w - vr * cf.w;
    ((float4*)out)[idx] = o;
}

// ---------------------------------------------------------------------------
extern "C" void kernel_launch(void* const* d_in, const int* in_sizes, int n_in,
                              void* d_out, int out_size, void* d_ws, size_t ws_size,
                              hipStream_t stream) {
    const float* A = (const float*)d_in[0];   // raw_update [4096, 16384] fp32
    const float* v = (const float*)d_in[1];   // v [4096] fp32
    float* out = (float*)d_out;

    // ws layout (floats): [0] denom | [64, 64+16384) coeff | [64+16384, ...) partials
    float* ws = (float*)d_ws;
    float* denom   = ws;
    float* coeff   = ws + 64;
    float* partial = ws + 64 + IN_FEATS;

    const size_t avail_floats = ws_size / sizeof(float);
    int nchunk = 64;
    while (nchunk > 1 &&
           (size_t)(64 + IN_FEATS) + (size_t)nchunk * IN_FEATS > avail_floats) {
        nchunk >>= 1;
    }
    const int rows_per_chunk = (OUT_FEATS + nchunk - 1) / nchunk;

    // 1. denom
    k_denom<<<1, 256, 0, stream>>>(v, denom);

    // 2. split-K GEMV partials: grid (16 col-blocks, nchunk row-chunks)
    dim3 g2(IN_FEATS / 4 / 256, nchunk);
    k_gemv_partial<<<g2, 256, 0, stream>>>(A, v, partial, rows_per_chunk);

    // 3. reduce partials -> coeff
    k_reduce<<<IN_FEATS / 4 / 256, 256, 0, stream>>>(partial, denom, coeff, nchunk);

    // 4. apply rank-1 update
    const size_t n4 = (size_t)OUT_FEATS * IN_FEATS / 4;   // 16,777,216 float4
    k_apply<<<(unsigned)(n4 / 256), 256, 0, stream>>>(A, v, coeff, out);
}

// Round 2
// 156.232 us; speedup vs baseline: 1.0903x; 1.0903x over previous
//
#include <hip/hip_runtime.h>
#include <cstddef>

typedef float f4 __attribute__((ext_vector_type(4)));

#define OUT_FEATS 4096
#define IN_FEATS  16384
#define NCOL4     (IN_FEATS / 4)   // 4096 float4 per row
#define EPS       1e-8f

// ---------------------------------------------------------------------------
// Kernel 1: split-K partial GEMV.
// partial[chunk][j] = sum_{r in chunk} v[r] * A[r][j]
// grid = (NCOL4/256, nchunk), block = 256. Each thread owns one float4 of
// columns; rows unrolled x4 with 4 independent accumulators (4 loads in
// flight per thread). rows_per_chunk = 4096/nchunk (power of 2, >= 64, so
// always divisible by 4). Normal loads: we WANT A retained in L3 for apply.
// ---------------------------------------------------------------------------
__global__ void k_gemv_partial(const f4* __restrict__ A4,
                               const float* __restrict__ v,
                               f4* __restrict__ partial,
                               int rows_per_chunk) {
    const int col4 = blockIdx.x * 256 + threadIdx.x;
    const int r0 = blockIdx.y * rows_per_chunk;

    f4 acc0 = 0.f, acc1 = 0.f, acc2 = 0.f, acc3 = 0.f;
    size_t base = (size_t)r0 * NCOL4 + col4;
    for (int r = 0; r < rows_per_chunk; r += 4) {
        const f4 a0 = A4[base];
        const f4 a1 = A4[base + (size_t)NCOL4];
        const f4 a2 = A4[base + (size_t)2 * NCOL4];
        const f4 a3 = A4[base + (size_t)3 * NCOL4];
        acc0 += v[r0 + r + 0] * a0;
        acc1 += v[r0 + r + 1] * a1;
        acc2 += v[r0 + r + 2] * a2;
        acc3 += v[r0 + r + 3] * a3;
        base += (size_t)4 * NCOL4;
    }
    const f4 tot = (acc0 + acc1) + (acc2 + acc3);
    partial[(size_t)blockIdx.y * NCOL4 + col4] = tot;
}

// ---------------------------------------------------------------------------
// Kernel 2: coeff[j] = (sum_c partial[c][j]) / (||v||^2 + eps)
// denom fused: each of the 16 blocks redundantly reduces v (16 KiB) — free.
// ---------------------------------------------------------------------------
__global__ void k_reduce(const f4* __restrict__ partial,
                         const float* __restrict__ v,
                         f4* __restrict__ coeff,
                         int nchunk) {
    __shared__ float red[4];
    float s = 0.f;
    for (int i = threadIdx.x; i < OUT_FEATS; i += 256) {
        const float x = v[i];
        s += x * x;
    }
    #pragma unroll
    for (int off = 32; off > 0; off >>= 1) s += __shfl_down(s, off, 64);
    if ((threadIdx.x & 63) == 0) red[threadIdx.x >> 6] = s;
    __syncthreads();
    const float denom = red[0] + red[1] + red[2] + red[3] + EPS;

    const int j4 = blockIdx.x * 256 + threadIdx.x;
    f4 acc = 0.f;
    for (int c = 0; c < nchunk; ++c)
        acc += partial[(size_t)c * NCOL4 + j4];
    coeff[j4] = acc / denom;
}

// ---------------------------------------------------------------------------
// Kernel 3: out[i][j] = A[i][j] - v[i] * coeff[j]
// Fully coalesced float4; row uniform per block. NON-TEMPORAL stores so the
// 256 MiB out stream doesn't evict A from the 256 MiB Infinity Cache —
// apply's A-reads (and next replay's GEMV reads) stay L3-resident.
// ---------------------------------------------------------------------------
__global__ void k_apply(const f4* __restrict__ A4,
                        const float* __restrict__ v,
                        const f4* __restrict__ coeff,
                        f4* __restrict__ out) {
    const size_t idx = (size_t)blockIdx.x * 256 + threadIdx.x;  // float4 index
    const int row = (int)(idx >> 12);        // / NCOL4
    const int c4  = (int)(idx & (NCOL4 - 1));
    const f4 a  = A4[idx];
    const f4 cf = coeff[c4];
    const float vr = v[row];
    const f4 o = a - vr * cf;
    __builtin_nontemporal_store(o, &out[idx]);
}

// ---------------------------------------------------------------------------
extern "C" void kernel_launch(void* const* d_in, const int* in_sizes, int n_in,
                              void* d_out, int out_size, void* d_ws, size_t ws_size,
                              hipStream_t stream) {
    const f4*    A4 = (const f4*)d_in[0];     // raw_update [4096, 16384] fp32
    const float* v  = (const float*)d_in[1];  // v [4096] fp32
    f4* out = (f4*)d_out;

    // ws layout (floats): [0, 16384) coeff | [16384, ...) partials
    float* ws = (float*)d_ws;
    f4* coeff   = (f4*)ws;
    f4* partial = (f4*)(ws + IN_FEATS);

    const size_t avail_floats = ws_size / sizeof(float);
    int nchunk = 64;
    while (nchunk > 1 &&
           (size_t)IN_FEATS + (size_t)nchunk * IN_FEATS > avail_floats) {
        nchunk >>= 1;
    }
    const int rows_per_chunk = OUT_FEATS / nchunk;   // power of 2, >= 64

    // 1. split-K GEMV partials
    dim3 g1(NCOL4 / 256, nchunk);
    k_gemv_partial<<<g1, 256, 0, stream>>>(A4, v, partial, rows_per_chunk);

    // 2. reduce partials (+ fused denom) -> coeff
    k_reduce<<<NCOL4 / 256, 256, 0, stream>>>(partial, v, coeff, nchunk);

    // 3. apply rank-1 update with nt stores
    const size_t n4 = (size_t)OUT_FEATS * IN_FEATS / 4;   // 16,777,216 float4
    k_apply<<<(unsigned)(n4 / 256), 256, 0, stream>>>(A4, v, coeff, out);
}

// Round 3
// 154.320 us; speedup vs baseline: 1.1038x; 1.0124x over previous
//
#include <hip/hip_runtime.h>
#include <cstddef>

typedef float f4 __attribute__((ext_vector_type(4)));

#define OUT_FEATS 4096
#define IN_FEATS  16384
#define NCOL4     (IN_FEATS / 4)   // 4096 float4 per row
#define EPS       1e-8f

#define W       16                 // columns owned per block (64 B per row)
#define BT      512                // threads per block (8 waves)
#define NBLK    (IN_FEATS / W)     // 1024 blocks
#define KITER   32                 // 4096 rows / 128 row-groups per block pass

// ---------------------------------------------------------------------------
// Single fused kernel. The op is column-separable: coeff[j] only needs
// column j of A. Block b owns columns [16b, 16b+16): it reads its stripe
// (4096 x 16 fp32 = 256 KiB) ONCE into registers (32 x f4 per thread),
// computes its coeff slice locally, applies, and nt-stores. A is read
// exactly once -> 512 MiB total HBM traffic instead of 768 MiB.
//
// Thread layout: T = 0..511; q = T&3 -> which float4 of the 64 B row
// segment; g = T>>2 -> row-group; thread handles rows g + 128k, k=0..31.
// A wave-wide load = 16 rows x 64 B contiguous segments (full lines).
// ---------------------------------------------------------------------------
__global__ void __launch_bounds__(BT, 2)
k_fused(const f4* __restrict__ A4,
        const float* __restrict__ v,
        f4* __restrict__ out) {
    __shared__ float vs[OUT_FEATS];   // staged v (16 KiB)
    __shared__ float red[8];          // per-wave ||v||^2 partials
    __shared__ f4    red2[32];        // 8 waves x 4 col-quads

    // XCD-chunked swizzle: 1024 blocks, 8 XCDs, 128 consecutive stripes/XCD
    const int b = (blockIdx.x & 7) * (NBLK / 8) + (blockIdx.x >> 3);

    const int T = threadIdx.x;
    const int q = T & 3;              // col-quad within the stripe
    const int g = T >> 2;             // row-group 0..127
    const int c4 = b * (W / 4) + q;   // global float4 column index

    // ---- 1. issue the full payload (32 independent f4 loads/thread) ----
    f4 a[KITER];
    const size_t base = (size_t)g * NCOL4 + c4;
    #pragma unroll
    for (int k = 0; k < KITER; ++k)
        a[k] = A4[base + (size_t)k * 128 * NCOL4];

    // ---- 2. stage v into LDS + local sum of squares ----
    float vsq = 0.f;
    {
        const f4* v4 = (const f4*)v;
        #pragma unroll
        for (int i = 0; i < 2; ++i) {
            const int idx = T + i * BT;          // f4 index 0..1023
            const f4 x = v4[idx];
            ((f4*)vs)[idx] = x;
            vsq += x.x * x.x + x.y * x.y + x.z * x.z + x.w * x.w;
        }
    }
    #pragma unroll
    for (int off = 32; off > 0; off >>= 1) vsq += __shfl_down(vsq, off, 64);
    if ((T & 63) == 0) red[T >> 6] = vsq;
    __syncthreads();
    const float denom = red[0] + red[1] + red[2] + red[3] +
                        red[4] + red[5] + red[6] + red[7] + EPS;

    // ---- 3. partial coeff over this thread's 32 rows ----
    f4 s = 0.f;
    #pragma unroll
    for (int k = 0; k < KITER; ++k)
        s += vs[g + 128 * k] * a[k];

    // ---- 4. reduce across the 16 lanes/wave sharing a col-quad ----
    // lanes with equal (lane&3) differ in bits 2..5 -> xor 4,8,16,32
    #pragma unroll
    for (int off = 4; off <= 32; off <<= 1) {
        s.x += __shfl_xor(s.x, off, 64);
        s.y += __shfl_xor(s.y, off, 64);
        s.z += __shfl_xor(s.z, off, 64);
        s.w += __shfl_xor(s.w, off, 64);
    }
    if ((T & 63) < 4) red2[(T >> 6) * 4 + q] = s;
    __syncthreads();

    // ---- 5. final coeff for this thread's col-quad ----
    f4 cf = red2[q];
    #pragma unroll
    for (int w2 = 1; w2 < 8; ++w2) cf += red2[w2 * 4 + q];
    cf = cf / denom;

    // ---- 6. apply rank-1 update + non-temporal store ----
    #pragma unroll
    for (int k = 0; k < KITER; ++k) {
        const f4 o = a[k] - vs[g + 128 * k] * cf;
        __builtin_nontemporal_store(o, &out[base + (size_t)k * 128 * NCOL4]);
    }
}

// ---------------------------------------------------------------------------
extern "C" void kernel_launch(void* const* d_in, const int* in_sizes, int n_in,
                              void* d_out, int out_size, void* d_ws, size_t ws_size,
                              hipStream_t stream) {
    const f4*    A4 = (const f4*)d_in[0];     // raw_update [4096, 16384] fp32
    const float* v  = (const float*)d_in[1];  // v [4096] fp32
    f4* out = (f4*)d_out;

    k_fused<<<NBLK, BT, 0, stream>>>(A4, v, out);
}